// Round 5
// baseline (539.104 us; speedup 1.0000x reference)
//
#include <hip/hip_runtime.h>
#include <hip/hip_bf16.h>
#include <stdint.h>

// ---------------------------------------------------------------------------
// RowParallelLinearSparse: out[M,N] = x[M,K] · (W ⊙ nm_mask)[N,K]^T + bias
// M=16384, N=2048, K=2048.
// R5: self-calibrating smfmac. probe_smfmac discovers the v_smfmac operand
// layout on-device (16 hypotheses vs exact integer reference), writes a flag;
// gemm_smfmac runs iff a hypothesis validated, else gemm_dense (R2-verified,
// 188us) runs. All launches unconditional & identical-work (graph-safe).
// ---------------------------------------------------------------------------

typedef short  bf16x4   __attribute__((ext_vector_type(4)));
typedef short  bf16x8   __attribute__((ext_vector_type(8)));
typedef short  bf16x16  __attribute__((ext_vector_type(16)));
typedef float  floatx4  __attribute__((ext_vector_type(4)));

#define AS1 __attribute__((address_space(1)))
#define AS3 __attribute__((address_space(3)))

__device__ __forceinline__ void async_copy16(const void* g, void* l) {
    __builtin_amdgcn_global_load_lds((const AS1 unsigned int*)g,
                                     (AS3 unsigned int*)l, 16, 0, 0);
}

__device__ __forceinline__ unsigned short f2bf(float f) {
    union { float f; unsigned int u; } v;
    v.f = f;
    unsigned int r = (v.u + 0x7fffu + ((v.u >> 16) & 1u)) >> 16;  // RNE
    return (unsigned short)r;
}

__device__ __forceinline__ floatx4 smfmac_bf16(bf16x8 a, bf16x16 b, floatx4 c,
                                               int idx) {
    asm volatile("v_smfmac_f32_16x16x64_bf16 %0, %1, %2, %3"
                 : "+v"(c) : "v"(a), "v"(b), "v"(idx));
    return c;
}

__device__ __forceinline__ unsigned swapnib(unsigned u) {
    return ((u & 0x3333u) << 2) | ((u >> 2) & 0x3333u);
}

// --- x: fp32 -> bf16, 8 elements/thread --------------------------------------
__global__ void cvt_bf16_x8(const float4* __restrict__ in,
                            uint4* __restrict__ out, long n8) {
    long i = (long)blockIdx.x * blockDim.x + threadIdx.x;
    if (i >= n8) return;
    float4 f0 = in[2 * i];
    float4 f1 = in[2 * i + 1];
    uint4 o;
    o.x = (unsigned)f2bf(f0.x) | ((unsigned)f2bf(f0.y) << 16);
    o.y = (unsigned)f2bf(f0.z) | ((unsigned)f2bf(f0.w) << 16);
    o.z = (unsigned)f2bf(f1.x) | ((unsigned)f2bf(f1.y) << 16);
    o.w = (unsigned)f2bf(f1.z) | ((unsigned)f2bf(f1.w) << 16);
    out[i] = o;
}

// --- W: 2:4 select (stable-argsort tie order). Emits compressed vals (pos
//     order) + 4-bit/group indices + DENSE masked bf16 (fallback path).
//     One thread = 2 groups (8 floats). ---------------------------------------
__global__ void sparsify_w2(const float4* __restrict__ W4,
                            uint2* __restrict__ Wc,
                            unsigned char* __restrict__ Widx,
                            uint4* __restrict__ Wd,
                            int n2) {
    int t = blockIdx.x * blockDim.x + threadIdx.x;
    if (t >= n2) return;
    unsigned short cvals[4];
    unsigned short dvals[8];
    unsigned nib[2];
#pragma unroll
    for (int g = 0; g < 2; g++) {
        float4 w4 = W4[2 * t + g];
        float v[4] = {w4.x, w4.y, w4.z, w4.w};
        float a[4] = {fabsf(w4.x), fabsf(w4.y), fabsf(w4.z), fabsf(w4.w)};
        int pos[2] = {0, 0};
        int c = 0;
#pragma unroll
        for (int i = 0; i < 4; i++) {
            int rank = 0;
#pragma unroll
            for (int j = 0; j < 4; j++)
                rank += (a[j] < a[i]) || (a[j] == a[i] && j < i);
            const bool keep = (rank >= 2);
            const unsigned short bv = keep ? f2bf(v[i]) : (unsigned short)0;
            dvals[4 * g + i] = bv;
            if (keep) { pos[c] = i; cvals[2 * g + c] = bv; c++; }
        }
        nib[g] = (unsigned)pos[0] | ((unsigned)pos[1] << 2);
    }
    uint2 oc;
    oc.x = (unsigned)cvals[0] | ((unsigned)cvals[1] << 16);
    oc.y = (unsigned)cvals[2] | ((unsigned)cvals[3] << 16);
    Wc[t] = oc;
    Widx[t] = (unsigned char)(nib[0] | (nib[1] << 4));
    uint4 od;
    od.x = (unsigned)dvals[0] | ((unsigned)dvals[1] << 16);
    od.y = (unsigned)dvals[2] | ((unsigned)dvals[3] << 16);
    od.z = (unsigned)dvals[4] | ((unsigned)dvals[5] << 16);
    od.w = (unsigned)dvals[6] | ((unsigned)dvals[7] << 16);
    Wd[t] = od;
}

// --- probe: discover smfmac operand layout. 1 block, 1 wave. ----------------
// Variant v: bit0 A-stacked, bit1 B-stacked, bit2 idx-nibble-swapped,
//            bit3 D-transposed.  Writes winner (0..15) or 255.
__global__ void probe_smfmac(unsigned* __restrict__ flag) {
    const int lane = threadIdx.x;
    const int q = lane >> 4, fm = lane & 15;
    const int P0[6] = {0, 0, 0, 1, 1, 2};
    const int P1[6] = {1, 2, 3, 2, 3, 3};
    unsigned winner = 255u;
    for (int v = 0; v < 16; ++v) {
        const int aS = v & 1, bS = (v >> 1) & 1;
        const int i1 = (v >> 2) & 1, dT = (v >> 3) & 1;
        // A fragment (sparse operand, its free dim index = fm)
        bf16x8 av;
        unsigned iv16 = 0;
        const int n = fm;
#pragma unroll
        for (int rp = 0; rp < 4; ++rp) {
            const int g = aS ? ((rp & 1) + 2 * q + 8 * (rp >> 1)) : (4 * q + rp);
            const int s6 = (n + g) % 6;
            const int p0 = P0[s6], p1 = P1[s6];
            av[2 * rp]     = (short)f2bf((float)(((n * 3 + (4 * g + p0) * 7) % 13) + 1));
            av[2 * rp + 1] = (short)f2bf((float)(((n * 3 + (4 * g + p1) * 7) % 13) + 1));
            unsigned nb = i1 ? ((unsigned)p1 | ((unsigned)p0 << 2))
                             : ((unsigned)p0 | ((unsigned)p1 << 2));
            iv16 |= nb << (4 * rp);
        }
        const int ivr = (int)(iv16 | (iv16 << 16));
        // B fragment (dense operand, free dim index = fm)
        bf16x16 bvv;
#pragma unroll
        for (int j = 0; j < 16; ++j) {
            const int k = bS ? ((j < 8) ? (q * 8 + j) : (32 + q * 8 + (j - 8)))
                             : (q * 16 + j);
            bvv[j] = (short)f2bf((float)(((k * 5 + fm * 11) % 13) + 1));
        }
        floatx4 acc = (floatx4){0.f, 0.f, 0.f, 0.f};
        acc = smfmac_bf16(av, bvv, acc, ivr);
        bool ok = true;
#pragma unroll
        for (int r = 0; r < 4; ++r) {
            const int nr = dT ? fm : (q * 4 + r);   // sparse-dim index of D elem
            const int mc = dT ? (q * 4 + r) : fm;   // dense-dim index
            float ref = 0.f;
            for (int g = 0; g < 16; ++g) {
                const int s6 = (nr + g) % 6;
                const int k0 = 4 * g + P0[s6], k1 = 4 * g + P1[s6];
                ref += (float)(((nr * 3 + k0 * 7) % 13) + 1) *
                       (float)(((k0 * 5 + mc * 11) % 13) + 1);
                ref += (float)(((nr * 3 + k1 * 7) % 13) + 1) *
                       (float)(((k1 * 5 + mc * 11) % 13) + 1);
            }
            ok = ok && (acc[r] == ref);
        }
        const bool allok = (__all((int)ok) != 0);
        if (allok && winner == 255u) winner = (unsigned)v;
    }
    if (lane == 0) *flag = winner;
}

// --- sparse GEMM: 128N x 128M block, KT=128/stage, 4 waves 2x2, variant-aware.
__global__ __launch_bounds__(256) void gemm_smfmac(
    const unsigned short* __restrict__ Wc,   // [N, K/2] bf16 compressed
    const unsigned char*  __restrict__ Wi,   // [N, K/8] idx bytes
    const unsigned short* __restrict__ X,    // [M, K]  bf16
    const float* __restrict__ bias,          // [N]
    float* __restrict__ C,                   // [M, N] fp32
    const unsigned* __restrict__ flagp,
    int M, int N, int K) {
    const unsigned fl = *flagp;
    if (fl == 255u) return;
    const int aS = fl & 1, bS = (fl >> 1) & 1;
    const int i1 = (fl >> 2) & 1, dT = (fl >> 3) & 1;

    __shared__ unsigned short lW[128 * 64];
    __shared__ unsigned short lX[2][128 * 64];
    __shared__ unsigned short lI[128 * 8];

    const int tid  = threadIdx.x;
    const int wid  = tid >> 6;
    const int lane = tid & 63;
    const int q    = lane >> 4;
    const int fm   = lane & 15;

    const int nbx = N >> 7;
    const int bn  = (blockIdx.x % nbx) * 128;
    const int bm  = (blockIdx.x / nbx) * 128;

    const int wn = (wid & 1) * 64;
    const int wm = (wid >> 1) * 64;

    const int s_row = lane >> 3;
    const int s_col = ((lane & 7) ^ s_row) * 8;

    const int Kc = K >> 1;
    const unsigned short* Wg = Wc + (size_t)(bn + wid * 32 + s_row) * Kc + s_col;
    const unsigned short* Xg = X  + (size_t)(bm + wid * 32 + s_row) * K  + s_col;
    const unsigned char*  Ig = Wi + (size_t)(bn + (wid & 1) * 64 + lane) * (K >> 3);

    unsigned short* lWw  = &lW[(wid * 32) * 64];
    unsigned short* lXw0 = &lX[0][(wid * 32) * 64];
    unsigned short* lXw1 = &lX[1][(wid * 32) * 64];
    unsigned short* lIw  = &lI[(wid & 1) * 64 * 8];

    // B chunk bases (branchless variant handling)
    const int cb0 = bS ? q : (2 * q);
    const int cb1 = bS ? (4 + q) : (2 * q + 1);

    floatx4 acc[4][4];
#pragma unroll
    for (int i = 0; i < 4; i++)
#pragma unroll
        for (int j = 0; j < 4; j++)
            acc[i][j] = (floatx4){0.f, 0.f, 0.f, 0.f};

    const int niter = K >> 7;
    for (int kt = 0; kt < niter; ++kt) {
#pragma unroll
        for (int ii = 0; ii < 4; ii++) {
            async_copy16(Wg + (size_t)ii * 8 * Kc,     lWw  + ii * 8 * 64);
            async_copy16(Xg + (size_t)ii * 8 * K,      lXw0 + ii * 8 * 64);
            async_copy16(Xg + (size_t)ii * 8 * K + 64, lXw1 + ii * 8 * 64);
        }
        if (wid < 2) async_copy16(Ig, lIw);
        __syncthreads();
        Wg += 64; Xg += 128; Ig += 16;

#pragma unroll
        for (int step = 0; step < 2; ++step) {
            bf16x8 aw[4];
            int iv[4];
            if (!aS) {
#pragma unroll
                for (int i = 0; i < 4; i++) {
                    const int row = wn + i * 16 + fm;
                    const int ch = ((step << 2) + q) ^ (row & 7);
                    aw[i] = *(const bf16x8*)&lW[row * 64 + ch * 8];
                    unsigned u = lI[row * 8 + (step << 2) + q];
                    if (i1) u = swapnib(u);
                    iv[i] = (int)(u | (u << 16));
                }
            } else {
#pragma unroll
                for (int i = 0; i < 4; i++) {
                    const int row = wn + i * 16 + fm;
                    const int cl = ((step << 2) + (q >> 1)) ^ (row & 7);
                    const int chh = ((step << 2) + 2 + (q >> 1)) ^ (row & 7);
                    const int off = (q & 1) * 4;
                    bf16x4 lo = *(const bf16x4*)&lW[row * 64 + cl * 8 + off];
                    bf16x4 hi = *(const bf16x4*)&lW[row * 64 + chh * 8 + off];
                    aw[i] = __builtin_shufflevector(lo, hi, 0, 1, 2, 3, 4, 5, 6, 7);
                    unsigned ua = lI[row * 8 + (step << 2) + (q >> 1)];
                    unsigned ub = lI[row * 8 + (step << 2) + 2 + (q >> 1)];
                    const int sh = (q & 1) * 8;
                    unsigned u = ((ua >> sh) & 0xFFu) | (((ub >> sh) & 0xFFu) << 8);
                    if (i1) u = swapnib(u);
                    iv[i] = (int)(u | (u << 16));
                }
            }
            bf16x16 bv[4];
#pragma unroll
            for (int j = 0; j < 4; j++) {
                const int row = wm + j * 16 + fm;
                const int c0 = cb0 ^ (row & 7);
                const int c1 = cb1 ^ (row & 7);
                bf16x8 lo = *(const bf16x8*)&lX[step][row * 64 + c0 * 8];
                bf16x8 hi = *(const bf16x8*)&lX[step][row * 64 + c1 * 8];
                bv[j] = __builtin_shufflevector(lo, hi, 0, 1, 2, 3, 4, 5, 6, 7,
                                                8, 9, 10, 11, 12, 13, 14, 15);
            }
#pragma unroll
            for (int i = 0; i < 4; i++)
#pragma unroll
                for (int j = 0; j < 4; j++)
                    acc[i][j] = smfmac_bf16(aw[i], bv[j], acc[i][j], iv[i]);
        }
        __syncthreads();
    }

    if (!dT) {
        // D: row=n (sparse dim), col=m -> lane stores float4 along N
#pragma unroll
        for (int i = 0; i < 4; i++) {
            const int n0 = bn + wn + i * 16 + q * 4;
            const float4 bv4 = *(const float4*)&bias[n0];
#pragma unroll
            for (int j = 0; j < 4; j++) {
                const int m = bm + wm + j * 16 + fm;
                float4 o;
                o.x = acc[i][j][0] + bv4.x;
                o.y = acc[i][j][1] + bv4.y;
                o.z = acc[i][j][2] + bv4.z;
                o.w = acc[i][j][3] + bv4.w;
                *(float4*)&C[(size_t)m * N + n0] = o;
            }
        }
    } else {
        // D transposed: row=m, col=n -> scalar stores down M
#pragma unroll
        for (int i = 0; i < 4; i++) {
            const int n = bn + wn + i * 16 + fm;
            const float bvs = bias[n];
#pragma unroll
            for (int j = 0; j < 4; j++) {
                const int m0 = bm + wm + j * 16 + q * 4;
#pragma unroll
                for (int r = 0; r < 4; r++)
                    C[(size_t)(m0 + r) * N + n] = acc[i][j][r] + bvs;
            }
        }
    }
}

// --- dense fallback: R2-verified kernel (XOR-swizzle, conflict-free). -------
__global__ __launch_bounds__(256) void gemm_dense(
    const unsigned short* __restrict__ A,   // [M,K] bf16 (x)
    const unsigned short* __restrict__ B,   // [N,K] bf16 (dense masked W)
    const float* __restrict__ bias,
    float* __restrict__ C,
    const unsigned* __restrict__ flagp,
    int M, int N, int K) {
    const unsigned fl = *flagp;
    if (fl != 255u) return;

    __shared__ unsigned short lA[128 * 64];
    __shared__ unsigned short lB[128 * 64];

    const int tid  = threadIdx.x;
    const int wid  = tid >> 6;
    const int lane = tid & 63;

    const int nbx = N >> 7;
    const int bn  = (blockIdx.x % nbx) * 128;
    const int bm  = (blockIdx.x / nbx) * 128;

    const int wm = (wid & 1) * 64;
    const int wn = (wid >> 1) * 64;

    const int s_row   = lane >> 3;
    const int s_chunk = lane & 7;
    const int s_col   = (s_chunk ^ s_row) * 8;

    const unsigned short* Ag = A + (size_t)(bm + wid * 32 + s_row) * K + s_col;
    const unsigned short* Bg = B + (size_t)(bn + wid * 32 + s_row) * K + s_col;
    unsigned short* lAw = &lA[(wid * 32) * 64];
    unsigned short* lBw = &lB[(wid * 32) * 64];

    floatx4 acc[4][4];
#pragma unroll
    for (int i = 0; i < 4; i++)
#pragma unroll
        for (int j = 0; j < 4; j++)
            acc[i][j] = (floatx4){0.f, 0.f, 0.f, 0.f};

    const int fm = lane & 15;
    const int q  = lane >> 4;
    const int sw = fm & 7;

    for (int kt = 0; kt < K; kt += 64) {
#pragma unroll
        for (int i = 0; i < 4; i++) {
            async_copy16(Ag + (size_t)i * 8 * K + kt, lAw + i * 8 * 64);
            async_copy16(Bg + (size_t)i * 8 * K + kt, lBw + i * 8 * 64);
        }
        __syncthreads();
#pragma unroll
        for (int ks = 0; ks < 2; ks++) {
            const int ko = ((ks * 4 + q) ^ sw) * 8;
            bf16x8 af[4], bfv[4];
#pragma unroll
            for (int i = 0; i < 4; i++) {
                af[i]  = *(const bf16x8*)&lA[(wm + i * 16 + fm) * 64 + ko];
                bfv[i] = *(const bf16x8*)&lB[(wn + i * 16 + fm) * 64 + ko];
            }
#pragma unroll
            for (int i = 0; i < 4; i++)
#pragma unroll
                for (int j = 0; j < 4; j++)
                    acc[i][j] = __builtin_amdgcn_mfma_f32_16x16x32_bf16(
                        af[i], bfv[j], acc[i][j], 0, 0, 0);
        }
        __syncthreads();
    }

    const int cn = lane & 15;
    const int cm = (lane >> 4) * 4;
#pragma unroll
    for (int j = 0; j < 4; j++) {
        const int col = bn + wn + j * 16 + cn;
        const float bv = bias[col];
#pragma unroll
        for (int i = 0; i < 4; i++) {
            const size_t rbase = (size_t)(bm + wm + i * 16 + cm) * N + col;
#pragma unroll
            for (int r = 0; r < 4; r++)
                C[rbase + (size_t)r * N] = acc[i][j][r] + bv;
        }
    }
}

extern "C" void kernel_launch(void* const* d_in, const int* in_sizes, int n_in,
                              void* d_out, int out_size, void* d_ws, size_t ws_size,
                              hipStream_t stream) {
    const float* x    = (const float*)d_in[0];
    const float* w    = (const float*)d_in[1];
    const float* bias = (const float*)d_in[2];
    float* out = (float*)d_out;

    const int O = in_sizes[2];
    const int H = in_sizes[1] / O;               // K
    const long M = (long)in_sizes[0] / H;        // 16384

    // ws layout: xb | wc | wi | flag(256B pad) | wb_dense
    char* wsp = (char*)d_ws;
    unsigned short* xb = (unsigned short*)wsp;
    size_t off = (size_t)M * H * 2;
    unsigned short* wc = (unsigned short*)(wsp + off);
    off += (size_t)O * H;                        // O*H/2 elems * 2B
    unsigned char* wix = (unsigned char*)(wsp + off);
    off += (size_t)O * H / 8;
    off = (off + 255) & ~(size_t)255;
    unsigned* flag = (unsigned*)(wsp + off);
    off += 256;
    unsigned short* wb = (unsigned short*)(wsp + off);

    const long n8 = (long)M * H / 8;
    cvt_bf16_x8<<<dim3((n8 + 255) / 256), dim3(256), 0, stream>>>(
        (const float4*)x, (uint4*)xb, n8);

    const int n2 = O * H / 8;
    sparsify_w2<<<dim3((n2 + 255) / 256), dim3(256), 0, stream>>>(
        (const float4*)w, (uint2*)wc, wix, (uint4*)wb, n2);

    probe_smfmac<<<dim3(1), dim3(64), 0, stream>>>(flag);

    const int nblocks = (int)((M / 128) * (O / 128));   // 2048
    gemm_smfmac<<<dim3(nblocks), dim3(256), 0, stream>>>(
        wc, wix, xb, bias, out, flag, (int)M, O, H);
    gemm_dense<<<dim3(nblocks), dim3(256), 0, stream>>>(
        xb, wb, bias, out, flag, (int)M, O, H);
}